// Round 8
// baseline (397.020 us; speedup 1.0000x reference)
//
#include <hip/hip_runtime.h>

#define NSEQ  1536
#define HEADS 8
#define NREL  3071   // 2N-1
#define NRELP 3072
#define KZ    4      // key splits in attn

typedef __bf16 bf16;
typedef __bf16 bf16x8 __attribute__((ext_vector_type(8)));
typedef __bf16 bf16x4 __attribute__((ext_vector_type(4)));
typedef float  f32x4  __attribute__((ext_vector_type(4)));

static __device__ __forceinline__ f32x4 mfma16(bf16x8 a, bf16x8 b, f32x4 c) {
  return __builtin_amdgcn_mfma_f32_16x16x32_bf16(a, b, c, 0, 0, 0);
}

// async global->LDS, 16B per lane; lds base wave-uniform (HW adds lane*16)
static __device__ __forceinline__ void gload_lds16(const bf16* g, bf16* l) {
  __builtin_amdgcn_global_load_lds((const __attribute__((address_space(1))) void*)g,
                                   (__attribute__((address_space(3))) void*)l, 16, 0, 0);
}

// DPP-based 16-lane (row) sum
#define DPP_F(v, ctrl) __int_as_float(__builtin_amdgcn_update_dpp(0, __float_as_int(v), ctrl, 0xF, 0xF, true))
static __device__ __forceinline__ float rowsum16(float v) {
  v += DPP_F(v, 0xB1);
  v += DPP_F(v, 0x4E);
  v += DPP_F(v, 0x124);
  v += DPP_F(v, 0x128);
  return v;
}

// ---------- one-launch prep: cast x, cast pos, transpose weights, zero merge flags ----------
// grid = 4608 (x cast) + 576 (pos cast) + 3168 (transposes: Wq768 Wk768 Wv768 Wout768 Wrel96) + 1 (flags) = 8353
__global__ __launch_bounds__(256) void prep(const float* __restrict__ x, const float* __restrict__ pos,
                                            const float* __restrict__ Wq, const float* __restrict__ Wk,
                                            const float* __restrict__ Wv, const float* __restrict__ Wout,
                                            const float* __restrict__ Wrel,
                                            bf16* __restrict__ xb, bf16* __restrict__ posb,
                                            bf16* __restrict__ WT, bf16* __restrict__ WoT,
                                            bf16* __restrict__ WrT, int* __restrict__ flags) {
  int blk = blockIdx.x;
  if (blk < 4608) {  // cast x
    int i = blk * 256 + threadIdx.x;
    float4 v = ((const float4*)x)[i];
    bf16x4 o;
    o[0] = (bf16)v.x; o[1] = (bf16)v.y; o[2] = (bf16)v.z; o[3] = (bf16)v.w;
    ((bf16x4*)xb)[i] = o;
    return;
  }
  blk -= 4608;
  if (blk < 576) {  // cast pos
    int i = blk * 256 + threadIdx.x;
    if (i < (NREL * 192 / 4)) {
      float4 v = ((const float4*)pos)[i];
      bf16x4 o;
      o[0] = (bf16)v.x; o[1] = (bf16)v.y; o[2] = (bf16)v.z; o[3] = (bf16)v.w;
      ((bf16x4*)posb)[i] = o;
    }
    return;
  }
  blk -= 576;
  if (blk >= 3168) {  // zero attn-merge flags (384 ints), exactly one block
    for (int i = threadIdx.x; i < 384; i += 256) flags[i] = 0;
    return;
  }
  const float* in; bf16* out; int C, ostride, orowoff, cx, ry;
  if (blk < 768)       { in = Wq;   out = WT;  C = 512;  ostride = 1536; orowoff = 0;    cx = blk % 16; ry = blk / 16; }
  else if (blk < 1536) { blk -= 768;  in = Wk;   out = WT;  C = 512;  ostride = 1536; orowoff = 512;  cx = blk % 16; ry = blk / 16; }
  else if (blk < 2304) { blk -= 1536; in = Wv;   out = WT;  C = 512;  ostride = 1536; orowoff = 1024; cx = blk % 16; ry = blk / 16; }
  else if (blk < 3072) { blk -= 2304; in = Wout; out = WoT; C = 1536; ostride = 512;  orowoff = 0;    cx = blk % 48; ry = blk / 48; }
  else                 { blk -= 3072; in = Wrel; out = WrT; C = 512;  ostride = 192;  orowoff = 0;    cx = blk % 16; ry = blk / 16; }
  __shared__ float t[32][33];
  int tx = threadIdx.x & 31, ty = threadIdx.x >> 5;
  int r0 = ry * 32, c0 = cx * 32;
#pragma unroll
  for (int i = 0; i < 4; i++)
    t[ty + 8 * i][tx] = in[(size_t)(r0 + ty + 8 * i) * C + c0 + tx];
  __syncthreads();
#pragma unroll
  for (int i = 0; i < 4; i++)
    out[(size_t)(c0 + ty + 8 * i + orowoff) * ostride + r0 + tx] = (bf16)t[tx][ty + 8 * i];
}

// ---------- shared GEMM core: 64(M)x128(N) tile, BK=64, XOR-swizzled LDS ----------
static __device__ __forceinline__ void gemm_core(const bf16* __restrict__ A, const bf16* __restrict__ BT,
                                                 int Klen, int ldk, int m0, int n0, int M,
                                                 bf16* sa, bf16* sb, f32x4 acc[4][2]) {
  int tid = threadIdx.x, wave = tid >> 6, lane = tid & 63;
  int l15 = lane & 15, quad = lane >> 4;
  int lrow = lane >> 3, lcg = lane & 7;
  for (int k0 = 0; k0 < Klen; k0 += 64) {
    __syncthreads();
#pragma unroll
    for (int t = 0; t < 2; t++) {
      int row = wave * 16 + t * 8 + lrow;
      int ra = m0 + row; if (ra > M - 1) ra = M - 1;
      gload_lds16(A + (size_t)ra * ldk + k0 + ((lcg ^ (row & 7)) * 8), sa + (wave * 16 + t * 8) * 64);
    }
#pragma unroll
    for (int t = 0; t < 4; t++) {
      int row = wave * 32 + t * 8 + lrow;
      gload_lds16(BT + (size_t)(n0 + row) * ldk + k0 + ((lcg ^ (row & 7)) * 8), sb + (wave * 32 + t * 8) * 64);
    }
    __syncthreads();
#pragma unroll
    for (int kq = 0; kq < 2; kq++) {
      bf16x8 af[4], bfr[2];
#pragma unroll
      for (int rt = 0; rt < 4; rt++) {
        int row = rt * 16 + l15;
        af[rt] = *(const bf16x8*)&sa[row * 64 + (((kq * 4 + quad) ^ (row & 7)) * 8)];
      }
#pragma unroll
      for (int ct = 0; ct < 2; ct++) {
        int row = wave * 32 + ct * 16 + l15;
        bfr[ct] = *(const bf16x8*)&sb[row * 64 + (((kq * 4 + quad) ^ (row & 7)) * 8)];
      }
#pragma unroll
      for (int ct = 0; ct < 2; ct++)
#pragma unroll
        for (int rt = 0; rt < 4; rt++)
          acc[rt][ct] = mfma16(af[rt], bfr[ct], acc[rt][ct]);
    }
  }
}

// ---------- fused qkv + rel GEMM ----------
// grid (48, 16): y 0-3 q, 4-7 k, 8-11 v (transposed), 12-15 rel (repacked)
__global__ __launch_bounds__(256) void gemm_qkvrel(const bf16* __restrict__ xb, const bf16* __restrict__ WT,
                                                   const bf16* __restrict__ posb, const bf16* __restrict__ WrT,
                                                   const float* __restrict__ cb, const float* __restrict__ pb,
                                                   bf16* __restrict__ qc, bf16* __restrict__ qp,
                                                   bf16* __restrict__ kb, bf16* __restrict__ vt,
                                                   bf16* __restrict__ rk) {
  __shared__ __align__(16) bf16 sa[64 * 64];
  __shared__ __align__(16) bf16 sb[128 * 64];
  __shared__ __align__(16) bf16 tv[64 * 130];
  int tid = threadIdx.x, wave = tid >> 6, lane = tid & 63;
  int l15 = lane & 15, quad = lane >> 4;
  int m0 = blockIdx.x * 64;
  f32x4 acc[4][2] = {};
  if (blockIdx.y >= 12) {  // rel path
    int n0 = (blockIdx.y - 12) * 128;
    gemm_core(posb, WrT, 192, 192, m0, n0, NREL, sa, sb, acc);
#pragma unroll
    for (int rt = 0; rt < 4; rt++)
#pragma unroll
      for (int ct = 0; ct < 2; ct++)
#pragma unroll
        for (int r = 0; r < 4; r++) {
          int row = m0 + rt * 16 + quad * 4 + r;
          if (row < NREL) {
            int col = n0 + wave * 32 + ct * 16 + l15;
            rk[((size_t)(col >> 6) * NRELP + row) * 64 + (col & 63)] = (bf16)acc[rt][ct][r];
          }
        }
    return;
  }
  int n0 = blockIdx.y * 128;
  gemm_core(xb, WT, 1536, 1536, m0, n0, 3072, sa, sb, acc);
  int b = m0 / NSEQ, nseq0 = m0 % NSEQ;
  if (blockIdx.y < 8) {
    bool isq = blockIdx.y < 4;
#pragma unroll
    for (int rt = 0; rt < 4; rt++)
#pragma unroll
      for (int ct = 0; ct < 2; ct++)
#pragma unroll
        for (int r = 0; r < 4; r++) {
          int row = nseq0 + rt * 16 + quad * 4 + r;
          int colg = n0 + wave * 32 + ct * 16 + l15;
          int col = colg & 511;
          int h = col >> 6, d = col & 63;
          size_t o = ((size_t)(b * 8 + h) * NSEQ + row) * 64 + d;
          float v = acc[rt][ct][r];
          if (isq) {
            float qv = v * 0.125f;
            qc[o] = (bf16)(qv + cb[col]);
            qp[o] = (bf16)(qv + pb[col]);
          } else {
            kb[o] = (bf16)v;
          }
        }
  } else {
    // v: transpose through LDS -> vt [bh][dv][n]
#pragma unroll
    for (int rt = 0; rt < 4; rt++)
#pragma unroll
      for (int ct = 0; ct < 2; ct++)
#pragma unroll
        for (int r = 0; r < 4; r++)
          tv[(rt * 16 + quad * 4 + r) * 130 + wave * 32 + ct * 16 + l15] = (bf16)acc[rt][ct][r];
    __syncthreads();
    int n = tid & 63, c0v = tid >> 6;
    int hbase = (blockIdx.y - 8) * 2;
#pragma unroll
    for (int hh = 0; hh < 2; hh++)
#pragma unroll
      for (int i = 0; i < 16; i++) {
        int dv = i * 4 + c0v;
        vt[((size_t)(b * 8 + hbase + hh) * 64 + dv) * NSEQ + nseq0 + n] = tv[n * 130 + hh * 64 + dv];
      }
  }
}

// ---------- output projection GEMM (+bias), fp32 out ----------
__global__ __launch_bounds__(256) void gemm_out(const bf16* __restrict__ A, const bf16* __restrict__ BT,
                                                float* __restrict__ C, const float* __restrict__ bias) {
  __shared__ __align__(16) bf16 sa[64 * 64];
  __shared__ __align__(16) bf16 sb[128 * 64];
  int tid = threadIdx.x, wave = tid >> 6, lane = tid & 63;
  int l15 = lane & 15, quad = lane >> 4;
  int m0 = blockIdx.x * 64, n0 = blockIdx.y * 128;
  f32x4 acc[4][2] = {};
  gemm_core(A, BT, 512, 512, m0, n0, 3072, sa, sb, acc);
#pragma unroll
  for (int rt = 0; rt < 4; rt++)
#pragma unroll
    for (int ct = 0; ct < 2; ct++)
#pragma unroll
      for (int r = 0; r < 4; r++) {
        int row = m0 + rt * 16 + quad * 4 + r;
        int col = n0 + wave * 32 + ct * 16 + l15;
        C[(size_t)row * 1536 + col] = acc[rt][ct][r] + bias[col];
      }
}

// ---------- fused flash attention v7b: slim LDS (pls overlays srel), kz=4, fused merge ----------
// grid (24 q-blocks of 64 rows, 16 bh, 4 kz); block 256 = 4 waves; wave w owns rows i0+16w..+16.
__global__ __launch_bounds__(256, 4) void attn(const bf16* __restrict__ qc, const bf16* __restrict__ qp,
                                               const bf16* __restrict__ kb, const bf16* __restrict__ vt,
                                               const bf16* __restrict__ rk,
                                               float* __restrict__ Opart, float* __restrict__ mlp,
                                               bf16* __restrict__ Ob, int* __restrict__ flags) {
  __shared__ __align__(16) bf16 sk[64 * 64];
  __shared__ __align__(16) bf16 sv[64 * 64];
  __shared__ __align__(16) bf16 srel[128 * 64];  // pls overlays srel[0..4608) after rel MFMAs
  __shared__ int sflag;
  int qb = blockIdx.x, bh = blockIdx.y, kz = blockIdx.z;
  int h = bh & 7;
  int i0 = qb * 64;
  int wave = threadIdx.x >> 6, lane = threadIdx.x & 63;
  int l15 = lane & 15, quad = lane >> 4;
  int lrow = lane >> 3, lcg = lane & 7;
  const bf16* qcb = qc + (size_t)bh * NSEQ * 64;
  const bf16* qpb = qp + (size_t)bh * NSEQ * 64;
  bf16* plsw = srel + wave * (16 * 72);  // 1152 elems/wave

  int qrow = i0 + wave * 16 + l15;
  bf16x8 aqc0 = *(const bf16x8*)(qcb + (size_t)qrow * 64 + quad * 8);
  bf16x8 aqc1 = *(const bf16x8*)(qcb + (size_t)qrow * 64 + 32 + quad * 8);
  bf16x8 aqp0 = *(const bf16x8*)(qpb + (size_t)qrow * 64 + quad * 8);
  bf16x8 aqp1 = *(const bf16x8*)(qpb + (size_t)qrow * 64 + 32 + quad * 8);

  // loop-invariant LDS read pointers (row&7 == l15&7 for all accessed rows)
  int swz0 = (quad ^ (l15 & 7)) * 8;
  int swz1 = ((quad + 4) ^ (l15 & 7)) * 8;
  int locbase = (3 - wave) * 16;
  const bf16* pk0 = sk + l15 * 64 + swz0;
  const bf16* pk1 = sk + l15 * 64 + swz1;
  const bf16* pv0 = sv + l15 * 64 + swz0;
  const bf16* pv1 = sv + l15 * 64 + swz1;
  const bf16* pr0 = srel + (locbase + l15) * 64 + swz0;
  const bf16* pr1 = srel + (locbase + l15) * 64 + swz1;
  const bf16* plr = plsw + l15 * 72 + quad * 8;       // PV A-frag read base
  bf16* plw = plsw + quad * 288 + l15;                // P write base: row quad*4+r, +r*72 +c*16

  // loop-invariant staging pointers (advance by constants per tile)
  int jbeg = kz * 384;
  int Rbase0 = 1472 + jbeg - i0;
  const bf16* kS[2]; const bf16* vS[2]; const bf16* rS[4];
  bf16* kD[2]; bf16* vD[2]; bf16* rD[4];
  int swzs = (lcg ^ lrow) * 8;
#pragma unroll
  for (int t = 0; t < 2; t++) {
    int row = wave * 16 + t * 8 + lrow;
    kS[t] = kb + (size_t)bh * NSEQ * 64 + (size_t)(jbeg + row) * 64 + swzs;
    vS[t] = vt + (size_t)bh * 64 * NSEQ + (size_t)row * NSEQ + jbeg + swzs;
    kD[t] = sk + (wave * 16 + t * 8) * 64;
    vD[t] = sv + (wave * 16 + t * 8) * 64;
  }
#pragma unroll
  for (int t = 0; t < 4; t++) {
    int loc = wave * 32 + t * 8 + lrow;
    rS[t] = rk + (size_t)h * NRELP * 64 + (size_t)(Rbase0 + loc) * 64 + swzs;
    rD[t] = srel + (wave * 32 + t * 8) * 64;
  }

  // band-shift cross-lane setup
  int bidx[4];
  bool hisel[4];
#pragma unroll
  for (int r = 0; r < 4; r++) {
    int rl = quad * 4 + r;
    bidx[r] = (quad * 16 + ((l15 + 15 - rl) & 15)) << 2;
    hisel[r] = l15 > rl;
  }

  f32x4 acco[4] = {};
  float li[4] = {0.0f, 0.0f, 0.0f, 0.0f};

  for (int jt = 0; jt < 6; jt++) {
    __syncthreads();  // previous tile's LDS reads (incl. pls in srel) done
#pragma unroll
    for (int t = 0; t < 2; t++) {
      gload_lds16(kS[t], kD[t]); kS[t] += 4096;
      gload_lds16(vS[t], vD[t]); vS[t] += 64;
    }
#pragma unroll
    for (int t = 0; t < 4; t++) {
      gload_lds16(rS[t], rD[t]); rS[t] += 4096;
    }
    __syncthreads();  // staging complete
    // ---- content scores ----
    f32x4 s[4] = {};
#pragma unroll
    for (int c = 0; c < 4; c++) {
      s[c] = mfma16(aqc0, *(const bf16x8*)(pk0 + c * 1024), s[c]);
      s[c] = mfma16(aqc1, *(const bf16x8*)(pk1 + c * 1024), s[c]);
    }
    // ---- banded rel scores ----
    f32x4 sb5[5];
#pragma unroll
    for (int cc = 0; cc < 5; cc++) {
      f32x4 z = {};
      z = mfma16(aqp0, *(const bf16x8*)(pr0 + cc * 1024), z);
      sb5[cc] = mfma16(aqp1, *(const bf16x8*)(pr1 + cc * 1024), z);
    }
    __syncthreads();  // all srel reads done -> pls overlay safe
    // ---- shift-gather via bpermute ----
#pragma unroll
    for (int r = 0; r < 4; r++) {
      float bp[5];
#pragma unroll
      for (int cc = 0; cc < 5; cc++)
        bp[cc] = __int_as_float(__builtin_amdgcn_ds_bpermute(bidx[r], __float_as_int(sb5[cc][r])));
#pragma unroll
      for (int c = 0; c < 4; c++)
        s[c][r] += hisel[r] ? bp[c + 1] : bp[c];
    }
    // ---- fixed-shift exp + accumulate ----
#pragma unroll
    for (int c = 0; c < 4; c++)
#pragma unroll
      for (int r = 0; r < 4; r++) {
        float p = __expf(s[c][r] - 8.0f);
        bf16 pbh = (bf16)p;
        li[r] += (float)pbh;
        plw[r * 72 + c * 16] = pbh;  // (quad*4+r)*72 + c*16 + l15
      }
    // ---- PV ----
#pragma unroll
    for (int ks = 0; ks < 2; ks++) {
      bf16x8 ap = *(const bf16x8*)(plr + ks * 32);
#pragma unroll
      for (int c = 0; c < 4; c++) {
        const bf16* pvb = (ks == 0) ? pv0 : pv1;
        bf16x8 bv = *(const bf16x8*)(pvb + c * 1024);
        acco[c] = mfma16(ap, bv, acco[c]);
      }
    }
  }
  // ---- final row sums + write unnormalized partials ----
#pragma unroll
  for (int r = 0; r < 4; r++)
    li[r] = rowsum16(li[r]);
  int qt16 = qb * 4 + wave;
  size_t pbase = ((size_t)(bh * 96 + qt16)) * KZ + kz;
#pragma unroll
  for (int c = 0; c < 4; c++)
#pragma unroll
    for (int r = 0; r < 4; r++)
      Opart[pbase * 1024 + (quad * 4 + r) * 64 + c * 16 + l15] = acco[c][r];
  if (l15 == 0) {
#pragma unroll
    for (int r = 0; r < 4; r++)
      mlp[pbase * 16 + quad * 4 + r] = li[r];
  }
  // ---- last-block-wins merge (device-scope) ----
  __threadfence();
  __syncthreads();
  if (threadIdx.x == 0) sflag = atomicAdd(&flags[bh * 24 + qb], 1);
  __syncthreads();
  if (sflag == KZ - 1) {
    __threadfence();  // acquire: other blocks' partials visible
    int t = threadIdx.x;
    int r = t >> 2, qo = (t & 3) * 16;
    int qt = qb * 4 + (r >> 4), r16 = r & 15;
    size_t ob = ((size_t)(bh * 96 + qt)) * KZ;
    float L = 0.0f;
    float o[16];
#pragma unroll
    for (int i = 0; i < 16; i++) o[i] = 0.0f;
#pragma unroll
    for (int z = 0; z < KZ; z++) {
      L += mlp[(ob + z) * 16 + r16];
      const float* P = Opart + (ob + z) * 1024 + r16 * 64 + qo;
#pragma unroll
      for (int i = 0; i < 4; i++) {
        f32x4 v = ((const f32x4*)P)[i];
#pragma unroll
        for (int j = 0; j < 4; j++) o[i * 4 + j] += v[j];
      }
    }
    float inv = 1.0f / L;
    int b = bh >> 3;
    bf16* dst = Ob + ((size_t)(b * NSEQ + i0 + r)) * 512 + h * 64 + qo;
    bf16x8 w0, w1;
#pragma unroll
    for (int j = 0; j < 8; j++) { w0[j] = (bf16)(o[j] * inv); w1[j] = (bf16)(o[8 + j] * inv); }
    ((bf16x8*)dst)[0] = w0;
    ((bf16x8*)dst)[1] = w1;
  }
}

extern "C" void kernel_launch(void* const* d_in, const int* in_sizes, int n_in,
                              void* d_out, int out_size, void* d_ws, size_t ws_size,
                              hipStream_t stream) {
  const float* x    = (const float*)d_in[0];
  const float* Wq   = (const float*)d_in[1];
  const float* Wk   = (const float*)d_in[2];
  const float* Wv   = (const float*)d_in[3];
  const float* Wrel = (const float*)d_in[4];
  const float* Wout = (const float*)d_in[5];
  const float* bout = (const float*)d_in[6];
  const float* cb   = (const float*)d_in[7];
  const float* pb   = (const float*)d_in[8];
  const float* pos  = (const float*)d_in[9];
  float* out = (float*)d_out;

  char* ws = (char*)d_ws;
  size_t off = 0;
  auto alloc = [&](size_t bytes) {
    char* p = ws + off;
    off = (off + bytes + 255) & ~(size_t)255;
    return p;
  };
  bf16*  xb    = (bf16*)alloc(3072UL * 1536 * 2);
  bf16*  WT    = (bf16*)alloc(1536UL * 1536 * 2);
  bf16*  WoT   = (bf16*)alloc(1536UL * 512 * 2);
  bf16*  WrT   = (bf16*)alloc(512UL * 192 * 2);
  bf16*  posb  = (bf16*)alloc((size_t)NREL * 192 * 2);
  bf16*  qcb   = (bf16*)alloc(16UL * NSEQ * 64 * 2);
  bf16*  qpb   = (bf16*)alloc(16UL * NSEQ * 64 * 2);
  bf16*  kbb   = (bf16*)alloc(16UL * NSEQ * 64 * 2);
  bf16*  vtb   = (bf16*)alloc(16UL * NSEQ * 64 * 2);
  bf16*  rkb   = (bf16*)alloc(8UL * NRELP * 64 * 2);
  bf16*  Ob    = (bf16*)alloc(3072UL * 512 * 2);
  float* Opart = (float*)alloc(16UL * 96 * KZ * 1024 * 4);
  float* mlpw  = (float*)alloc(16UL * 96 * KZ * 16 * 4);
  int*   flags = (int*)alloc(384 * 4);

  // 1. casts + weight transposes + flag zeroing
  prep<<<dim3(8353), 256, 0, stream>>>(x, pos, Wq, Wk, Wv, Wout, Wrel, xb, posb, WT, WoT, WrT, flags);
  // 2. fused qkv + rel projections with repack epilogues
  gemm_qkvrel<<<dim3(48, 16), 256, 0, stream>>>(xb, WT, posb, WrT, cb, pb, qcb, qpb, kbb, vtb, rkb);
  // 3. fused flash attention (kz=4) with last-block merge -> Ob
  attn<<<dim3(24, 16, KZ), 256, 0, stream>>>(qcb, qpb, kbb, vtb, rkb, Opart, mlpw, Ob, flags);
  // 4. output projection + bias
  gemm_out<<<dim3(48, 12), 256, 0, stream>>>(Ob, WoT, out, bout);
}

// Round 9
// 179.024 us; speedup vs baseline: 2.2177x; 2.2177x over previous
//
#include <hip/hip_runtime.h>

#define NSEQ  1536
#define HEADS 8
#define NREL  3071   // 2N-1
#define NRELP 3072
#define KZ    4      // key splits in attn

typedef __bf16 bf16;
typedef __bf16 bf16x8 __attribute__((ext_vector_type(8)));
typedef __bf16 bf16x4 __attribute__((ext_vector_type(4)));
typedef float  f32x4  __attribute__((ext_vector_type(4)));

static __device__ __forceinline__ f32x4 mfma16(bf16x8 a, bf16x8 b, f32x4 c) {
  return __builtin_amdgcn_mfma_f32_16x16x32_bf16(a, b, c, 0, 0, 0);
}

// async global->LDS, 16B per lane; lds base wave-uniform (HW adds lane*16)
static __device__ __forceinline__ void gload_lds16(const bf16* g, bf16* l) {
  __builtin_amdgcn_global_load_lds((const __attribute__((address_space(1))) void*)g,
                                   (__attribute__((address_space(3))) void*)l, 16, 0, 0);
}

// DPP-based 16-lane (row) sum
#define DPP_F(v, ctrl) __int_as_float(__builtin_amdgcn_update_dpp(0, __float_as_int(v), ctrl, 0xF, 0xF, true))
static __device__ __forceinline__ float rowsum16(float v) {
  v += DPP_F(v, 0xB1);
  v += DPP_F(v, 0x4E);
  v += DPP_F(v, 0x124);
  v += DPP_F(v, 0x128);
  return v;
}

// ---------- one-launch prep: cast x, cast pos, transpose weights ----------
// grid = 4608 (x cast) + 576 (pos cast) + 3168 (transposes) = 8352
__global__ __launch_bounds__(256) void prep(const float* __restrict__ x, const float* __restrict__ pos,
                                            const float* __restrict__ Wq, const float* __restrict__ Wk,
                                            const float* __restrict__ Wv, const float* __restrict__ Wout,
                                            const float* __restrict__ Wrel,
                                            bf16* __restrict__ xb, bf16* __restrict__ posb,
                                            bf16* __restrict__ WT, bf16* __restrict__ WoT,
                                            bf16* __restrict__ WrT) {
  int blk = blockIdx.x;
  if (blk < 4608) {  // cast x
    int i = blk * 256 + threadIdx.x;
    float4 v = ((const float4*)x)[i];
    bf16x4 o;
    o[0] = (bf16)v.x; o[1] = (bf16)v.y; o[2] = (bf16)v.z; o[3] = (bf16)v.w;
    ((bf16x4*)xb)[i] = o;
    return;
  }
  blk -= 4608;
  if (blk < 576) {  // cast pos
    int i = blk * 256 + threadIdx.x;
    if (i < (NREL * 192 / 4)) {
      float4 v = ((const float4*)pos)[i];
      bf16x4 o;
      o[0] = (bf16)v.x; o[1] = (bf16)v.y; o[2] = (bf16)v.z; o[3] = (bf16)v.w;
      ((bf16x4*)posb)[i] = o;
    }
    return;
  }
  blk -= 576;
  const float* in; bf16* out; int C, ostride, orowoff, cx, ry;
  if (blk < 768)       { in = Wq;   out = WT;  C = 512;  ostride = 1536; orowoff = 0;    cx = blk % 16; ry = blk / 16; }
  else if (blk < 1536) { blk -= 768;  in = Wk;   out = WT;  C = 512;  ostride = 1536; orowoff = 512;  cx = blk % 16; ry = blk / 16; }
  else if (blk < 2304) { blk -= 1536; in = Wv;   out = WT;  C = 512;  ostride = 1536; orowoff = 1024; cx = blk % 16; ry = blk / 16; }
  else if (blk < 3072) { blk -= 2304; in = Wout; out = WoT; C = 1536; ostride = 512;  orowoff = 0;    cx = blk % 48; ry = blk / 48; }
  else                 { blk -= 3072; in = Wrel; out = WrT; C = 512;  ostride = 192;  orowoff = 0;    cx = blk % 16; ry = blk / 16; }
  __shared__ float t[32][33];
  int tx = threadIdx.x & 31, ty = threadIdx.x >> 5;
  int r0 = ry * 32, c0 = cx * 32;
#pragma unroll
  for (int i = 0; i < 4; i++)
    t[ty + 8 * i][tx] = in[(size_t)(r0 + ty + 8 * i) * C + c0 + tx];
  __syncthreads();
#pragma unroll
  for (int i = 0; i < 4; i++)
    out[(size_t)(c0 + ty + 8 * i + orowoff) * ostride + r0 + tx] = (bf16)t[tx][ty + 8 * i];
}

// ---------- shared GEMM core: 64(M)x128(N) tile, BK=64, XOR-swizzled LDS ----------
static __device__ __forceinline__ void gemm_core(const bf16* __restrict__ A, const bf16* __restrict__ BT,
                                                 int Klen, int ldk, int m0, int n0, int M,
                                                 bf16* sa, bf16* sb, f32x4 acc[4][2]) {
  int tid = threadIdx.x, wave = tid >> 6, lane = tid & 63;
  int l15 = lane & 15, quad = lane >> 4;
  int lrow = lane >> 3, lcg = lane & 7;
  for (int k0 = 0; k0 < Klen; k0 += 64) {
    __syncthreads();
#pragma unroll
    for (int t = 0; t < 2; t++) {
      int row = wave * 16 + t * 8 + lrow;
      int ra = m0 + row; if (ra > M - 1) ra = M - 1;
      gload_lds16(A + (size_t)ra * ldk + k0 + ((lcg ^ (row & 7)) * 8), sa + (wave * 16 + t * 8) * 64);
    }
#pragma unroll
    for (int t = 0; t < 4; t++) {
      int row = wave * 32 + t * 8 + lrow;
      gload_lds16(BT + (size_t)(n0 + row) * ldk + k0 + ((lcg ^ (row & 7)) * 8), sb + (wave * 32 + t * 8) * 64);
    }
    __syncthreads();
#pragma unroll
    for (int kq = 0; kq < 2; kq++) {
      bf16x8 af[4], bfr[2];
#pragma unroll
      for (int rt = 0; rt < 4; rt++) {
        int row = rt * 16 + l15;
        af[rt] = *(const bf16x8*)&sa[row * 64 + (((kq * 4 + quad) ^ (row & 7)) * 8)];
      }
#pragma unroll
      for (int ct = 0; ct < 2; ct++) {
        int row = wave * 32 + ct * 16 + l15;
        bfr[ct] = *(const bf16x8*)&sb[row * 64 + (((kq * 4 + quad) ^ (row & 7)) * 8)];
      }
#pragma unroll
      for (int ct = 0; ct < 2; ct++)
#pragma unroll
        for (int rt = 0; rt < 4; rt++)
          acc[rt][ct] = mfma16(af[rt], bfr[ct], acc[rt][ct]);
    }
  }
}

// ---------- fused qkv + rel GEMM ----------
// grid (48, 16): y 0-3 q, 4-7 k, 8-11 v (transposed), 12-15 rel (repacked)
__global__ __launch_bounds__(256) void gemm_qkvrel(const bf16* __restrict__ xb, const bf16* __restrict__ WT,
                                                   const bf16* __restrict__ posb, const bf16* __restrict__ WrT,
                                                   const float* __restrict__ cb, const float* __restrict__ pb,
                                                   bf16* __restrict__ qc, bf16* __restrict__ qp,
                                                   bf16* __restrict__ kb, bf16* __restrict__ vt,
                                                   bf16* __restrict__ rk) {
  __shared__ __align__(16) bf16 sa[64 * 64];
  __shared__ __align__(16) bf16 sb[128 * 64];
  __shared__ __align__(16) bf16 tv[64 * 130];
  int tid = threadIdx.x, wave = tid >> 6, lane = tid & 63;
  int l15 = lane & 15, quad = lane >> 4;
  int m0 = blockIdx.x * 64;
  f32x4 acc[4][2] = {};
  if (blockIdx.y >= 12) {  // rel path
    int n0 = (blockIdx.y - 12) * 128;
    gemm_core(posb, WrT, 192, 192, m0, n0, NREL, sa, sb, acc);
#pragma unroll
    for (int rt = 0; rt < 4; rt++)
#pragma unroll
      for (int ct = 0; ct < 2; ct++)
#pragma unroll
        for (int r = 0; r < 4; r++) {
          int row = m0 + rt * 16 + quad * 4 + r;
          if (row < NREL) {
            int col = n0 + wave * 32 + ct * 16 + l15;
            rk[((size_t)(col >> 6) * NRELP + row) * 64 + (col & 63)] = (bf16)acc[rt][ct][r];
          }
        }
    return;
  }
  int n0 = blockIdx.y * 128;
  gemm_core(xb, WT, 1536, 1536, m0, n0, 3072, sa, sb, acc);
  int b = m0 / NSEQ, nseq0 = m0 % NSEQ;
  if (blockIdx.y < 8) {
    bool isq = blockIdx.y < 4;
#pragma unroll
    for (int rt = 0; rt < 4; rt++)
#pragma unroll
      for (int ct = 0; ct < 2; ct++)
#pragma unroll
        for (int r = 0; r < 4; r++) {
          int row = nseq0 + rt * 16 + quad * 4 + r;
          int colg = n0 + wave * 32 + ct * 16 + l15;
          int col = colg & 511;
          int h = col >> 6, d = col & 63;
          size_t o = ((size_t)(b * 8 + h) * NSEQ + row) * 64 + d;
          float v = acc[rt][ct][r];
          if (isq) {
            float qv = v * 0.125f;
            qc[o] = (bf16)(qv + cb[col]);
            qp[o] = (bf16)(qv + pb[col]);
          } else {
            kb[o] = (bf16)v;
          }
        }
  } else {
    // v: transpose through LDS -> vt [bh][dv][n]
#pragma unroll
    for (int rt = 0; rt < 4; rt++)
#pragma unroll
      for (int ct = 0; ct < 2; ct++)
#pragma unroll
        for (int r = 0; r < 4; r++)
          tv[(rt * 16 + quad * 4 + r) * 130 + wave * 32 + ct * 16 + l15] = (bf16)acc[rt][ct][r];
    __syncthreads();
    int n = tid & 63, c0v = tid >> 6;
    int hbase = (blockIdx.y - 8) * 2;
#pragma unroll
    for (int hh = 0; hh < 2; hh++)
#pragma unroll
      for (int i = 0; i < 16; i++) {
        int dv = i * 4 + c0v;
        vt[((size_t)(b * 8 + hbase + hh) * 64 + dv) * NSEQ + nseq0 + n] = tv[n * 130 + hh * 64 + dv];
      }
  }
}

// ---------- output projection GEMM (+bias), fp32 out ----------
__global__ __launch_bounds__(256) void gemm_out(const bf16* __restrict__ A, const bf16* __restrict__ BT,
                                                float* __restrict__ C, const float* __restrict__ bias) {
  __shared__ __align__(16) bf16 sa[64 * 64];
  __shared__ __align__(16) bf16 sb[128 * 64];
  int tid = threadIdx.x, wave = tid >> 6, lane = tid & 63;
  int l15 = lane & 15, quad = lane >> 4;
  int m0 = blockIdx.x * 64, n0 = blockIdx.y * 128;
  f32x4 acc[4][2] = {};
  gemm_core(A, BT, 512, 512, m0, n0, 3072, sa, sb, acc);
#pragma unroll
  for (int rt = 0; rt < 4; rt++)
#pragma unroll
    for (int ct = 0; ct < 2; ct++)
#pragma unroll
      for (int r = 0; r < 4; r++) {
        int row = m0 + rt * 16 + quad * 4 + r;
        int col = n0 + wave * 32 + ct * 16 + l15;
        C[(size_t)row * 1536 + col] = acc[rt][ct][r] + bias[col];
      }
}

// ---------- fused flash attention v8: slim LDS (pls overlays srel), kz=4, NO device fences ----------
// grid (24 q-blocks of 64 rows, 16 bh, 4 kz); block 256 = 4 waves; wave w owns rows i0+16w..+16.
__global__ __launch_bounds__(256, 4) void attn(const bf16* __restrict__ qc, const bf16* __restrict__ qp,
                                               const bf16* __restrict__ kb, const bf16* __restrict__ vt,
                                               const bf16* __restrict__ rk,
                                               float* __restrict__ Opart, float* __restrict__ mlp) {
  __shared__ __align__(16) bf16 sk[64 * 64];
  __shared__ __align__(16) bf16 sv[64 * 64];
  __shared__ __align__(16) bf16 srel[128 * 64];  // pls overlays srel[0..4608) after rel MFMAs
  int qb = blockIdx.x, bh = blockIdx.y, kz = blockIdx.z;
  int h = bh & 7;
  int i0 = qb * 64;
  int wave = threadIdx.x >> 6, lane = threadIdx.x & 63;
  int l15 = lane & 15, quad = lane >> 4;
  int lrow = lane >> 3, lcg = lane & 7;
  const bf16* qcb = qc + (size_t)bh * NSEQ * 64;
  const bf16* qpb = qp + (size_t)bh * NSEQ * 64;
  bf16* plsw = srel + wave * (16 * 72);  // 1152 elems/wave

  int qrow = i0 + wave * 16 + l15;
  bf16x8 aqc0 = *(const bf16x8*)(qcb + (size_t)qrow * 64 + quad * 8);
  bf16x8 aqc1 = *(const bf16x8*)(qcb + (size_t)qrow * 64 + 32 + quad * 8);
  bf16x8 aqp0 = *(const bf16x8*)(qpb + (size_t)qrow * 64 + quad * 8);
  bf16x8 aqp1 = *(const bf16x8*)(qpb + (size_t)qrow * 64 + 32 + quad * 8);

  // loop-invariant LDS read pointers (row&7 == l15&7 for all accessed rows)
  int swz0 = (quad ^ (l15 & 7)) * 8;
  int swz1 = ((quad + 4) ^ (l15 & 7)) * 8;
  int locbase = (3 - wave) * 16;
  const bf16* pk0 = sk + l15 * 64 + swz0;
  const bf16* pk1 = sk + l15 * 64 + swz1;
  const bf16* pv0 = sv + l15 * 64 + swz0;
  const bf16* pv1 = sv + l15 * 64 + swz1;
  const bf16* pr0 = srel + (locbase + l15) * 64 + swz0;
  const bf16* pr1 = srel + (locbase + l15) * 64 + swz1;
  const bf16* plr = plsw + l15 * 72 + quad * 8;       // PV A-frag read base
  bf16* plw = plsw + quad * 288 + l15;                // P write base: +r*72 +c*16

  // loop-invariant staging pointers (advance by constants per tile)
  int jbeg = kz * 384;
  int Rbase0 = 1472 + jbeg - i0;
  const bf16* kS[2]; const bf16* vS[2]; const bf16* rS[4];
  bf16* kD[2]; bf16* vD[2]; bf16* rD[4];
  int swzs = (lcg ^ lrow) * 8;
#pragma unroll
  for (int t = 0; t < 2; t++) {
    int row = wave * 16 + t * 8 + lrow;
    kS[t] = kb + (size_t)bh * NSEQ * 64 + (size_t)(jbeg + row) * 64 + swzs;
    vS[t] = vt + (size_t)bh * 64 * NSEQ + (size_t)row * NSEQ + jbeg + swzs;
    kD[t] = sk + (wave * 16 + t * 8) * 64;
    vD[t] = sv + (wave * 16 + t * 8) * 64;
  }
#pragma unroll
  for (int t = 0; t < 4; t++) {
    int loc = wave * 32 + t * 8 + lrow;
    rS[t] = rk + (size_t)h * NRELP * 64 + (size_t)(Rbase0 + loc) * 64 + swzs;
    rD[t] = srel + (wave * 32 + t * 8) * 64;
  }

  // band-shift cross-lane setup
  int bidx[4];
  bool hisel[4];
#pragma unroll
  for (int r = 0; r < 4; r++) {
    int rl = quad * 4 + r;
    bidx[r] = (quad * 16 + ((l15 + 15 - rl) & 15)) << 2;
    hisel[r] = l15 > rl;
  }

  f32x4 acco[4] = {};
  float li[4] = {0.0f, 0.0f, 0.0f, 0.0f};

  for (int jt = 0; jt < 6; jt++) {
    __syncthreads();  // previous tile's LDS reads (incl. pls in srel) done
#pragma unroll
    for (int t = 0; t < 2; t++) {
      gload_lds16(kS[t], kD[t]); kS[t] += 4096;
      gload_lds16(vS[t], vD[t]); vS[t] += 64;
    }
#pragma unroll
    for (int t = 0; t < 4; t++) {
      gload_lds16(rS[t], rD[t]); rS[t] += 4096;
    }
    __syncthreads();  // staging complete
    // ---- content scores ----
    f32x4 s[4] = {};
#pragma unroll
    for (int c = 0; c < 4; c++) {
      s[c] = mfma16(aqc0, *(const bf16x8*)(pk0 + c * 1024), s[c]);
      s[c] = mfma16(aqc1, *(const bf16x8*)(pk1 + c * 1024), s[c]);
    }
    // ---- banded rel scores ----
    f32x4 sb5[5];
#pragma unroll
    for (int cc = 0; cc < 5; cc++) {
      f32x4 z = {};
      z = mfma16(aqp0, *(const bf16x8*)(pr0 + cc * 1024), z);
      sb5[cc] = mfma16(aqp1, *(const bf16x8*)(pr1 + cc * 1024), z);
    }
    __syncthreads();  // all srel reads done -> pls overlay safe
    // ---- shift-gather via bpermute ----
#pragma unroll
    for (int r = 0; r < 4; r++) {
      float bp[5];
#pragma unroll
      for (int cc = 0; cc < 5; cc++)
        bp[cc] = __int_as_float(__builtin_amdgcn_ds_bpermute(bidx[r], __float_as_int(sb5[cc][r])));
#pragma unroll
      for (int c = 0; c < 4; c++)
        s[c][r] += hisel[r] ? bp[c + 1] : bp[c];
    }
    // ---- fixed-shift exp + accumulate ----
#pragma unroll
    for (int c = 0; c < 4; c++)
#pragma unroll
      for (int r = 0; r < 4; r++) {
        float p = __expf(s[c][r] - 8.0f);
        bf16 pbh = (bf16)p;
        li[r] += (float)pbh;
        plw[r * 72 + c * 16] = pbh;  // (quad*4+r)*72 + c*16 + l15
      }
    // ---- PV ----
#pragma unroll
    for (int ks = 0; ks < 2; ks++) {
      bf16x8 ap = *(const bf16x8*)(plr + ks * 32);
#pragma unroll
      for (int c = 0; c < 4; c++) {
        const bf16* pvb = (ks == 0) ? pv0 : pv1;
        bf16x8 bv = *(const bf16x8*)(pvb + c * 1024);
        acco[c] = mfma16(ap, bv, acco[c]);
      }
    }
  }
  // ---- final row sums + write unnormalized partials ----
#pragma unroll
  for (int r = 0; r < 4; r++)
    li[r] = rowsum16(li[r]);
  int qt16 = qb * 4 + wave;
  size_t pbase = ((size_t)(bh * 96 + qt16)) * KZ + kz;
#pragma unroll
  for (int c = 0; c < 4; c++)
#pragma unroll
    for (int r = 0; r < 4; r++)
      Opart[pbase * 1024 + (quad * 4 + r) * 64 + c * 16 + l15] = acco[c][r];
  if (l15 == 0) {
#pragma unroll
    for (int r = 0; r < 4; r++)
      mlp[pbase * 16 + quad * 4 + r] = li[r];
  }
}

// ---------- merge the KZ key-split partials -> O bf16 [b][n][h][dv] ----------
__global__ void attn_merge(const float* __restrict__ Opart, const float* __restrict__ mlp,
                           bf16* __restrict__ O) {
  int qt = blockIdx.x, bh = blockIdx.y;
  int b = bh >> 3, h = bh & 7;
  int col = threadIdx.x & 63, rg = threadIdx.x >> 6;
  size_t base = (size_t)(bh * 96 + qt) * KZ;
#pragma unroll
  for (int rr = 0; rr < 4; rr++) {
    int row = rg * 4 + rr;
    float L = 0.0f, v = 0.0f;
#pragma unroll
    for (int z = 0; z < KZ; z++) {
      L += mlp[(base + z) * 16 + row];
      v += Opart[(base + z) * 1024 + row * 64 + col];
    }
    O[((size_t)(b * NSEQ + qt * 16 + row) * 8 + h) * 64 + col] = (bf16)(v / L);
  }
}

extern "C" void kernel_launch(void* const* d_in, const int* in_sizes, int n_in,
                              void* d_out, int out_size, void* d_ws, size_t ws_size,
                              hipStream_t stream) {
  const float* x    = (const float*)d_in[0];
  const float* Wq   = (const float*)d_in[1];
  const float* Wk   = (const float*)d_in[2];
  const float* Wv   = (const float*)d_in[3];
  const float* Wrel = (const float*)d_in[4];
  const float* Wout = (const float*)d_in[5];
  const float* bout = (const float*)d_in[6];
  const float* cb   = (const float*)d_in[7];
  const float* pb   = (const float*)d_in[8];
  const float* pos  = (const float*)d_in[9];
  float* out = (float*)d_out;

  char* ws = (char*)d_ws;
  size_t off = 0;
  auto alloc = [&](size_t bytes) {
    char* p = ws + off;
    off = (off + bytes + 255) & ~(size_t)255;
    return p;
  };
  bf16*  xb    = (bf16*)alloc(3072UL * 1536 * 2);
  bf16*  WT    = (bf16*)alloc(1536UL * 1536 * 2);
  bf16*  WoT   = (bf16*)alloc(1536UL * 512 * 2);
  bf16*  WrT   = (bf16*)alloc(512UL * 192 * 2);
  bf16*  posb  = (bf16*)alloc((size_t)NREL * 192 * 2);
  bf16*  qcb   = (bf16*)alloc(16UL * NSEQ * 64 * 2);
  bf16*  qpb   = (bf16*)alloc(16UL * NSEQ * 64 * 2);
  bf16*  kbb   = (bf16*)alloc(16UL * NSEQ * 64 * 2);
  bf16*  vtb   = (bf16*)alloc(16UL * NSEQ * 64 * 2);
  bf16*  rkb   = (bf16*)alloc(8UL * NRELP * 64 * 2);
  bf16*  Ob    = (bf16*)alloc(3072UL * 512 * 2);
  float* Opart = (float*)alloc(16UL * 96 * KZ * 1024 * 4);
  float* mlpw  = (float*)alloc(16UL * 96 * KZ * 16 * 4);

  // 1. casts + weight transposes
  prep<<<dim3(8352), 256, 0, stream>>>(x, pos, Wq, Wk, Wv, Wout, Wrel, xb, posb, WT, WoT, WrT);
  // 2. fused qkv + rel projections with repack epilogues
  gemm_qkvrel<<<dim3(48, 16), 256, 0, stream>>>(xb, WT, posb, WrT, cb, pb, qcb, qpb, kbb, vtb, rkb);
  // 3. fused flash attention (kz=4, slim LDS)
  attn<<<dim3(24, 16, KZ), 256, 0, stream>>>(qcb, qpb, kbb, vtb, rkb, Opart, mlpw);
  // 4. merge key-split partials
  attn_merge<<<dim3(96, 16), 256, 0, stream>>>(Opart, mlpw, Ob);
  // 5. output projection + bias
  gemm_out<<<dim3(48, 12), 256, 0, stream>>>(Ob, WoT, out, bout);
}